// Round 4
// baseline (452.068 us; speedup 1.0000x reference)
//
#include <hip/hip_runtime.h>
#include <hip/hip_bf16.h>

#define HIST 50
#define N_ITEMS 100000

typedef __bf16 bf8 __attribute__((ext_vector_type(8)));
typedef float  f4  __attribute__((ext_vector_type(4)));

__device__ __forceinline__ unsigned short f2bf(float x) {
    unsigned u = __builtin_bit_cast(unsigned, x);
    u += 0x7fffu + ((u >> 16) & 1u);          // RNE
    return (unsigned short)(u >> 16);
}
__device__ __forceinline__ float bf2f(unsigned b) {
    unsigned u = b << 16;
    return __builtin_bit_cast(float, u);
}

// ---------------------------------------------------------------------------
// Weight packer: fp32 [K][N] -> bf16 MFMA B-fragments. (unchanged from r2)
// Frag unit (nt, ks, lane l): 8 bf16 = B[ks*32 + (l>>4)*8 + j][nt*16 + (l&15)]
// stored contiguously at frag index (nt*KS + ks)*64 + l  (16 B per lane).
// ---------------------------------------------------------------------------
__global__ void pack_weights(const float* __restrict__ W1i, const float* __restrict__ W2i,
                             const float* __restrict__ W1u, const float* __restrict__ W2u,
                             unsigned short* __restrict__ dstbase)
{
    int i = blockIdx.x * 256 + threadIdx.x;   // 57344 total
    const float* W; unsigned short* dst; int N, KS, loc;
    if (i < 24576)      { W = W1i; dst = dstbase;          N = 512; KS = 12; loc = i; }          // 384x512
    else if (i < 32768) { W = W2i; dst = dstbase + 196608; N = 128; KS = 16; loc = i - 24576; }  // 512x128
    else if (i < 49152) { W = W1u; dst = dstbase + 262144; N = 512; KS = 8;  loc = i - 32768; }  // 256x512
    else                { W = W2u; dst = dstbase + 393216; N = 128; KS = 16; loc = i - 49152; }  // 512x128
    int l = loc & 63, fi = loc >> 6;
    int ks = fi % KS, nt = fi / KS;
    int q = l >> 4, c = l & 15;
    const float* src = W + (size_t)(ks * 32 + q * 8) * N + nt * 16 + c;
    unsigned o[4];
    #pragma unroll
    for (int k = 0; k < 4; ++k) {
        unsigned lo = f2bf(src[(2 * k) * N]);
        unsigned hi = f2bf(src[(2 * k + 1) * N]);
        o[k] = lo | (hi << 16);
    }
    uint4 v; v.x = o[0]; v.y = o[1]; v.z = o[2]; v.w = o[3];
    ((uint4*)dst)[(size_t)(nt * KS + ks) * 64 + l] = v;
}

// ---------------------------------------------------------------------------
// Item kernel: M-tile = 128 rows/block, 4 waves, wave tile 64x64.
// Layer1 in 4 col-chunks of 128; H chunk in LDS; layer2 partial-K per chunk.
// A stride 392 shorts (784 B = 49*16: odd 16B-granule factor -> good bank
// spread for ds_read_b128). H stride 136 shorts (272 B = 17*16, same).
// ---------------------------------------------------------------------------
#define RS 392
#define HSd 136

__global__ __launch_bounds__(256, 1) void item_kernel(
    const float* __restrict__ text, const float* __restrict__ gcn,
    const bf8* __restrict__ w1f, const float* __restrict__ b1,
    const bf8* __restrict__ w2f, const float* __restrict__ b2,
    unsigned short* __restrict__ item_bf)
{
    __shared__ __align__(16) unsigned short As[128 * RS];    // 100352 B
    __shared__ __align__(16) unsigned short Hs[128 * HSd];   // 34816 B
    __shared__ float b1s[512], b2s[128], sumsq[128];
    const int tid = threadIdx.x;
    const int row0 = blockIdx.x * 128;
    const int nval = min(128, N_ITEMS - row0);

    // ---- stage A = concat(text, gcn) as bf16 ----
    const float4* t4 = (const float4*)text;
    const float4* g4 = (const float4*)gcn;
    #pragma unroll
    for (int j = 0; j < 32; ++j) {            // text: 128 x 256
        int idx = tid + j * 256; int r = idx >> 6, c4 = idx & 63;
        float4 x = (r < nval) ? t4[(size_t)(row0 + r) * 64 + c4] : make_float4(0.f,0.f,0.f,0.f);
        ushort4 s; s.x = f2bf(x.x); s.y = f2bf(x.y); s.z = f2bf(x.z); s.w = f2bf(x.w);
        *(ushort4*)(As + r * RS + c4 * 4) = s;
    }
    #pragma unroll
    for (int j = 0; j < 16; ++j) {            // gcn: 128 x 128
        int idx = tid + j * 256; int r = idx >> 5, c4 = idx & 31;
        float4 x = (r < nval) ? g4[(size_t)(row0 + r) * 32 + c4] : make_float4(0.f,0.f,0.f,0.f);
        ushort4 s; s.x = f2bf(x.x); s.y = f2bf(x.y); s.z = f2bf(x.z); s.w = f2bf(x.w);
        *(ushort4*)(As + r * RS + 256 + c4 * 4) = s;
    }
    b1s[tid] = b1[tid]; b1s[tid + 256] = b1[tid + 256];
    if (tid < 128) { b2s[tid] = b2[tid]; sumsq[tid] = 0.0f; }
    __syncthreads();

    const int l = tid & 63, w = tid >> 6;
    const int q = l >> 4, c = l & 15;
    const int rbase = (w & 1) * 64;           // wave's row-half
    const int cbase = (w >> 1) * 64;          // wave's col-half (within 128 chunk)

    f4 acc2[4][4];
    #pragma unroll
    for (int i = 0; i < 4; ++i)
        #pragma unroll
        for (int j = 0; j < 4; ++j) acc2[i][j] = (f4)0.0f;

    const unsigned short* ap = As + (size_t)(rbase + c) * RS + q * 8;
    const unsigned short* hp = Hs + (size_t)(rbase + c) * HSd + q * 8;

    #pragma unroll 1
    for (int cc = 0; cc < 4; ++cc) {
        // ---- layer 1: chunk cols [cc*128, cc*128+128) ----
        f4 acc1[4][4];
        #pragma unroll
        for (int i = 0; i < 4; ++i)
            #pragma unroll
            for (int j = 0; j < 4; ++j) acc1[i][j] = (f4)0.0f;

        const bf8* w1p = w1f + (size_t)((cc * 8 + (w >> 1) * 4) * 12) * 64 + l;
        #pragma unroll
        for (int ks = 0; ks < 12; ++ks) {
            bf8 a[4], b[4];
            #pragma unroll
            for (int rt = 0; rt < 4; ++rt)
                a[rt] = *(const bf8*)(ap + rt * 16 * RS + ks * 32);
            #pragma unroll
            for (int nt = 0; nt < 4; ++nt)
                b[nt] = w1p[(size_t)(nt * 12 + ks) * 64];
            #pragma unroll
            for (int rt = 0; rt < 4; ++rt)
                #pragma unroll
                for (int nt = 0; nt < 4; ++nt)
                    acc1[rt][nt] = __builtin_amdgcn_mfma_f32_16x16x32_bf16(a[rt], b[nt], acc1[rt][nt], 0, 0, 0);
        }

        if (cc > 0) __syncthreads();          // prior chunk's H readers done
        // bias + relu -> Hs
        #pragma unroll
        for (int nt = 0; nt < 4; ++nt) {
            float bias = b1s[cc * 128 + cbase + nt * 16 + c];
            #pragma unroll
            for (int rt = 0; rt < 4; ++rt)
                #pragma unroll
                for (int reg = 0; reg < 4; ++reg) {
                    float h = fmaxf(acc1[rt][nt][reg] + bias, 0.0f);
                    Hs[(size_t)(rbase + rt * 16 + q * 4 + reg) * HSd + cbase + nt * 16 + c] = f2bf(h);
                }
        }
        __syncthreads();

        // ---- layer 2 partial: K-slice [cc*128, cc*128+128) ----
        #pragma unroll
        for (int ks2 = 0; ks2 < 4; ++ks2) {
            bf8 a[4], b[4];
            #pragma unroll
            for (int rt = 0; rt < 4; ++rt)
                a[rt] = *(const bf8*)(hp + rt * 16 * HSd + ks2 * 32);
            #pragma unroll
            for (int nt = 0; nt < 4; ++nt)
                b[nt] = w2f[(size_t)(((cbase >> 4) + nt) * 16 + cc * 4 + ks2) * 64 + l];
            #pragma unroll
            for (int rt = 0; rt < 4; ++rt)
                #pragma unroll
                for (int nt = 0; nt < 4; ++nt)
                    acc2[rt][nt] = __builtin_amdgcn_mfma_f32_16x16x32_bf16(a[rt], b[nt], acc2[rt][nt], 0, 0, 0);
        }
    }

    // ---- epilogue: +b2, l2norm, store bf16 ----
    float v[4][4][4];
    #pragma unroll
    for (int rt = 0; rt < 4; ++rt)
        #pragma unroll
        for (int nt = 0; nt < 4; ++nt) {
            float bias = b2s[cbase + nt * 16 + c];
            #pragma unroll
            for (int reg = 0; reg < 4; ++reg)
                v[rt][nt][reg] = acc2[rt][nt][reg] + bias;
        }
    #pragma unroll
    for (int rt = 0; rt < 4; ++rt)
        #pragma unroll
        for (int reg = 0; reg < 4; ++reg) {
            float s = 0.f;
            #pragma unroll
            for (int nt = 0; nt < 4; ++nt) s += v[rt][nt][reg] * v[rt][nt][reg];
            s += __shfl_xor(s, 1); s += __shfl_xor(s, 2);
            s += __shfl_xor(s, 4); s += __shfl_xor(s, 8);
            if (c == 0) atomicAdd(&sumsq[rbase + rt * 16 + q * 4 + reg], s);
        }
    __syncthreads();
    #pragma unroll
    for (int rt = 0; rt < 4; ++rt)
        #pragma unroll
        for (int reg = 0; reg < 4; ++reg) {
            int row = rbase + rt * 16 + q * 4 + reg;
            if (row < nval) {
                float inv = 1.0f / fmaxf(sqrtf(sumsq[row]), 1e-12f);
                #pragma unroll
                for (int nt = 0; nt < 4; ++nt)
                    item_bf[(size_t)(row0 + row) * 128 + cbase + nt * 16 + c] =
                        f2bf(v[rt][nt][reg] * inv);
            }
        }
}

// ---------------------------------------------------------------------------
// User tower (unchanged from r3: passed). 32 users/block.
// ---------------------------------------------------------------------------
template<int KS1, int ASTR, bool OUT_BF16>
__device__ __forceinline__ void two_layer(
    unsigned short* U,
    const float* b1s, const float* b2s, float* sumsq,
    const bf8* __restrict__ w1f, const bf8* __restrict__ w2f,
    void* __restrict__ outp, int row0, int tid)
{
    const int HSTR = 520;
    const int l = tid & 63, w = tid >> 6;
    const int q = l >> 4, c = l & 15;

    f4 acc1[2][8];
    #pragma unroll
    for (int i = 0; i < 2; ++i)
        #pragma unroll
        for (int j = 0; j < 8; ++j) acc1[i][j] = (f4)0.0f;

    const unsigned short* a0p = U + c * ASTR + q * 8;
    const unsigned short* a1p = U + (16 + c) * ASTR + q * 8;
    const bf8* wp = w1f + (size_t)(w * 8) * KS1 * 64 + l;
    #pragma unroll
    for (int ks = 0; ks < KS1; ++ks) {
        bf8 a0 = *(const bf8*)(a0p + ks * 32);
        bf8 a1 = *(const bf8*)(a1p + ks * 32);
        #pragma unroll
        for (int nt = 0; nt < 8; ++nt) {
            bf8 b = wp[(size_t)nt * KS1 * 64 + ks * 64];
            acc1[0][nt] = __builtin_amdgcn_mfma_f32_16x16x32_bf16(a0, b, acc1[0][nt], 0, 0, 0);
            acc1[1][nt] = __builtin_amdgcn_mfma_f32_16x16x32_bf16(a1, b, acc1[1][nt], 0, 0, 0);
        }
    }
    __syncthreads();
    unsigned short* Hsu = U;
    #pragma unroll
    for (int nt = 0; nt < 8; ++nt) {
        int col = (w * 8 + nt) * 16 + c;
        float bias = b1s[col];
        #pragma unroll
        for (int rt = 0; rt < 2; ++rt)
            #pragma unroll
            for (int reg = 0; reg < 4; ++reg) {
                float h = fmaxf(acc1[rt][nt][reg] + bias, 0.0f);
                Hsu[(rt * 16 + q * 4 + reg) * HSTR + col] = f2bf(h);
            }
    }
    __syncthreads();

    f4 acc2[2][2];
    #pragma unroll
    for (int i = 0; i < 2; ++i)
        #pragma unroll
        for (int j = 0; j < 2; ++j) acc2[i][j] = (f4)0.0f;

    const unsigned short* h0p = Hsu + c * HSTR + q * 8;
    const unsigned short* h1p = Hsu + (16 + c) * HSTR + q * 8;
    #pragma unroll
    for (int ks = 0; ks < 16; ++ks) {
        bf8 a0 = *(const bf8*)(h0p + ks * 32);
        bf8 a1 = *(const bf8*)(h1p + ks * 32);
        #pragma unroll
        for (int j = 0; j < 2; ++j) {
            bf8 b = w2f[(size_t)((w * 2 + j) * 16 + ks) * 64 + l];
            acc2[0][j] = __builtin_amdgcn_mfma_f32_16x16x32_bf16(a0, b, acc2[0][j], 0, 0, 0);
            acc2[1][j] = __builtin_amdgcn_mfma_f32_16x16x32_bf16(a1, b, acc2[1][j], 0, 0, 0);
        }
    }
    float v[2][2][4];
    #pragma unroll
    for (int rt = 0; rt < 2; ++rt)
        #pragma unroll
        for (int j = 0; j < 2; ++j)
            #pragma unroll
            for (int reg = 0; reg < 4; ++reg)
                v[rt][j][reg] = acc2[rt][j][reg] + b2s[(w * 2 + j) * 16 + c];
    #pragma unroll
    for (int rt = 0; rt < 2; ++rt)
        #pragma unroll
        for (int reg = 0; reg < 4; ++reg) {
            float s = v[rt][0][reg] * v[rt][0][reg] + v[rt][1][reg] * v[rt][1][reg];
            s += __shfl_xor(s, 1); s += __shfl_xor(s, 2);
            s += __shfl_xor(s, 4); s += __shfl_xor(s, 8);
            if (c == 0) atomicAdd(&sumsq[rt * 16 + q * 4 + reg], s);
        }
    __syncthreads();
    #pragma unroll
    for (int rt = 0; rt < 2; ++rt)
        #pragma unroll
        for (int reg = 0; reg < 4; ++reg) {
            int row = rt * 16 + q * 4 + reg;
            float inv = 1.0f / fmaxf(sqrtf(sumsq[row]), 1e-12f);
            #pragma unroll
            for (int j = 0; j < 2; ++j) {
                int col = (w * 2 + j) * 16 + c;
                float o = v[rt][j][reg] * inv;
                if (OUT_BF16)
                    ((unsigned short*)outp)[(size_t)(row0 + row) * 128 + col] = f2bf(o);
                else
                    ((float*)outp)[(size_t)(row0 + row) * 128 + col] = o;
            }
        }
}

__global__ __launch_bounds__(256, 4) void user_kernel(
    const float* __restrict__ gcnu, const int* __restrict__ hist,
    const unsigned short* __restrict__ item_bf,
    const bf8* __restrict__ w1f, const float* __restrict__ b1,
    const bf8* __restrict__ w2f, const float* __restrict__ b2,
    float* __restrict__ outp)
{
    __shared__ __align__(16) unsigned short U[32 * 520];
    __shared__ float b1s[512], b2s[128], sumsq[32];
    const int tid = threadIdx.x;
    const int u0 = blockIdx.x * 32;
    int* histL = (int*)(U + 32 * 272);
    const float4* g4 = (const float4*)gcnu;
    #pragma unroll
    for (int j = 0; j < 4; ++j) {
        int idx = tid + j * 256; int r = idx >> 5, c4 = idx & 31;
        float4 x = g4[(size_t)(u0 + r) * 32 + c4];
        ushort4 s; s.x = f2bf(x.x); s.y = f2bf(x.y); s.z = f2bf(x.z); s.w = f2bf(x.w);
        *(ushort4*)(U + r * 272 + c4 * 4) = s;
    }
    for (int i = tid; i < 32 * HIST; i += 256)
        histL[i] = hist[(size_t)u0 * HIST + i];
    b1s[tid] = b1[tid]; b1s[tid + 256] = b1[tid + 256];
    if (tid < 128) b2s[tid] = b2[tid];
    if (tid < 32)  sumsq[tid] = 0.0f;
    __syncthreads();
    {
        const int u = tid >> 3, g = tid & 7;
        float f[16];
        #pragma unroll
        for (int k = 0; k < 16; ++k) f[k] = 0.0f;
        const int* hrow = histL + u * HIST;
        #pragma unroll 5
        for (int t = 0; t < HIST; ++t) {
            int id = hrow[t];
            const uint4* p = (const uint4*)(item_bf + (size_t)id * 128 + g * 16);
            uint4 x0 = p[0], x1 = p[1];
            unsigned vs[8] = {x0.x, x0.y, x0.z, x0.w, x1.x, x1.y, x1.z, x1.w};
            #pragma unroll
            for (int k = 0; k < 8; ++k) {
                f[2 * k]     += bf2f(vs[k] & 0xffffu);
                f[2 * k + 1] += bf2f(vs[k] >> 16);
            }
        }
        unsigned o[8];
        #pragma unroll
        for (int k = 0; k < 8; ++k)
            o[k] = (unsigned)f2bf(f[2 * k] * 0.02f) | ((unsigned)f2bf(f[2 * k + 1] * 0.02f) << 16);
        uint4 s0; s0.x = o[0]; s0.y = o[1]; s0.z = o[2]; s0.w = o[3];
        uint4 s1; s1.x = o[4]; s1.y = o[5]; s1.z = o[6]; s1.w = o[7];
        *(uint4*)(U + u * 272 + 128 + g * 16) = s0;
        *(uint4*)(U + u * 272 + 128 + g * 16 + 8) = s1;
    }
    __syncthreads();
    two_layer<8, 272, false>(U, b1s, b2s, sumsq, w1f, w2f, outp, u0, tid);
}

extern "C" void kernel_launch(void* const* d_in, const int* in_sizes, int n_in,
                              void* d_out, int out_size, void* d_ws, size_t ws_size,
                              hipStream_t stream) {
    const float* text = (const float*)d_in[0];   // [100000,256]
    const float* gcni = (const float*)d_in[1];   // [100000,128]
    const float* gcnu = (const float*)d_in[2];   // [16384,128]
    const int*   hist = (const int*)d_in[3];     // [16384,50]
    const float* W1i  = (const float*)d_in[4];   // [384,512]
    const float* b1i  = (const float*)d_in[5];
    const float* W2i  = (const float*)d_in[6];   // [512,128]
    const float* b2i  = (const float*)d_in[7];
    const float* W1u  = (const float*)d_in[8];   // [256,512]
    const float* b1u  = (const float*)d_in[9];
    const float* W2u  = (const float*)d_in[10];  // [512,128]
    const float* b2u  = (const float*)d_in[11];
    float* out = (float*)d_out;                  // [16384,128] fp32

    unsigned short* itemb = (unsigned short*)d_ws;   // 25.6 MB bf16 item_emb
    unsigned short* pw = itemb + 12800000;           // packed weights (0.9 MB)

    pack_weights<<<224, 256, 0, stream>>>(W1i, W2i, W1u, W2u, pw);
    item_kernel<<<(N_ITEMS + 127) / 128, 256, 0, stream>>>(
        text, gcni, (const bf8*)pw, b1i, (const bf8*)(pw + 196608), b2i, itemb);
    user_kernel<<<16384 / 32, 256, 0, stream>>>(
        gcnu, hist, itemb, (const bf8*)(pw + 262144), b1u, (const bf8*)(pw + 393216), b2u, out);
}

// Round 5
// 342.718 us; speedup vs baseline: 1.3191x; 1.3191x over previous
//
#include <hip/hip_runtime.h>
#include <hip/hip_bf16.h>

#define HIST 50
#define N_ITEMS 100000
#define N_USERS 16384

typedef __bf16 bf8 __attribute__((ext_vector_type(8)));
typedef float  f4  __attribute__((ext_vector_type(4)));

__device__ __forceinline__ unsigned short f2bf(float x) {
    unsigned u = __builtin_bit_cast(unsigned, x);
    u += 0x7fffu + ((u >> 16) & 1u);          // RNE
    return (unsigned short)(u >> 16);
}
__device__ __forceinline__ float bf2f(unsigned b) {
    unsigned u = b << 16;
    return __builtin_bit_cast(float, u);
}

// ---------------------------------------------------------------------------
// Weight packer: fp32 [K][N] -> bf16 MFMA B-fragments. (verified r2-r4)
// Frag unit (nt, ks, lane l): 8 bf16 = B[ks*32 + (l>>4)*8 + j][nt*16 + (l&15)]
// stored at frag index (nt*KS + ks)*64 + l (16 B per lane).
// ---------------------------------------------------------------------------
__global__ void pack_weights(const float* __restrict__ W1i, const float* __restrict__ W2i,
                             const float* __restrict__ W1u, const float* __restrict__ W2u,
                             unsigned short* __restrict__ dstbase)
{
    int i = blockIdx.x * 256 + threadIdx.x;   // 57344 total
    const float* W; unsigned short* dst; int N, KS, loc;
    if (i < 24576)      { W = W1i; dst = dstbase;          N = 512; KS = 12; loc = i; }
    else if (i < 32768) { W = W2i; dst = dstbase + 196608; N = 128; KS = 16; loc = i - 24576; }
    else if (i < 49152) { W = W1u; dst = dstbase + 262144; N = 512; KS = 8;  loc = i - 32768; }
    else                { W = W2u; dst = dstbase + 393216; N = 128; KS = 16; loc = i - 49152; }
    int l = loc & 63, fi = loc >> 6;
    int ks = fi % KS, nt = fi / KS;
    int q = l >> 4, c = l & 15;
    const float* src = W + (size_t)(ks * 32 + q * 8) * N + nt * 16 + c;
    unsigned o[4];
    #pragma unroll
    for (int k = 0; k < 4; ++k) {
        unsigned lo = f2bf(src[(2 * k) * N]);
        unsigned hi = f2bf(src[(2 * k + 1) * N]);
        o[k] = lo | (hi << 16);
    }
    uint4 v; v.x = o[0]; v.y = o[1]; v.z = o[2]; v.w = o[3];
    ((uint4*)dst)[(size_t)(nt * KS + ks) * 64 + l] = v;
}

// ---------------------------------------------------------------------------
// Core: 64 rows, 2-layer MLP + l2norm. 4 waves; layer1 wave-tile 64x128
// (acc1[4][8], 32 MFMA per K-step vs 4 LDS + 8 global loads). A (stride ASTR
// shorts, 16B-multiple with odd 16B-granule factor -> even LDS bank spread)
// lives in union buffer U; H (stride 520) overwrites it after barrier 1.
// MFMA 16x16x32 bf16: A-frag m=l&15,k=q*8+j; B n=l&15,k same; D row=q*4+reg,
// col=l&15 (m89-verified).
// ---------------------------------------------------------------------------
template<int KS1, int ASTR, bool OUT_BF16>
__device__ __forceinline__ void tower_core(
    unsigned short* U, const float* b1s, const float* b2s, float* sumsq,
    const bf8* __restrict__ w1f, const bf8* __restrict__ w2f,
    void* __restrict__ outp, int row0, int nval, int tid)
{
    const int HSTR = 520;                     // 1040 B = 65*16: even bank spread
    const int l = tid & 63, w = tid >> 6;
    const int q = l >> 4, c = l & 15;

    f4 acc1[4][8];
    #pragma unroll
    for (int i = 0; i < 4; ++i)
        #pragma unroll
        for (int j = 0; j < 8; ++j) acc1[i][j] = (f4)0.0f;

    const unsigned short* ap = U + c * ASTR + q * 8;
    #pragma unroll
    for (int ks = 0; ks < KS1; ++ks) {
        bf8 a[4], b[8];
        #pragma unroll
        for (int rt = 0; rt < 4; ++rt)
            a[rt] = *(const bf8*)(ap + rt * 16 * ASTR + ks * 32);
        #pragma unroll
        for (int nt = 0; nt < 8; ++nt)
            b[nt] = w1f[(size_t)((w * 8 + nt) * KS1 + ks) * 64 + l];
        #pragma unroll
        for (int rt = 0; rt < 4; ++rt)
            #pragma unroll
            for (int nt = 0; nt < 8; ++nt)
                acc1[rt][nt] = __builtin_amdgcn_mfma_f32_16x16x32_bf16(a[rt], b[nt], acc1[rt][nt], 0, 0, 0);
    }
    __syncthreads();                          // all A reads done; U becomes H

    #pragma unroll
    for (int nt = 0; nt < 8; ++nt) {
        int col = w * 128 + nt * 16 + c;
        float bias = b1s[col];
        #pragma unroll
        for (int rt = 0; rt < 4; ++rt)
            #pragma unroll
            for (int reg = 0; reg < 4; ++reg) {
                float h = fmaxf(acc1[rt][nt][reg] + bias, 0.0f);
                U[(rt * 16 + q * 4 + reg) * HSTR + col] = f2bf(h);
            }
    }
    __syncthreads();

    // layer 2: K=512 (16 k-steps), wave w owns cols [w*32, w*32+32)
    f4 acc2[4][2];
    #pragma unroll
    for (int i = 0; i < 4; ++i)
        #pragma unroll
        for (int j = 0; j < 2; ++j) acc2[i][j] = (f4)0.0f;

    const unsigned short* hp = U + c * HSTR + q * 8;
    #pragma unroll
    for (int ks = 0; ks < 16; ++ks) {
        bf8 a[4], b[2];
        #pragma unroll
        for (int rt = 0; rt < 4; ++rt)
            a[rt] = *(const bf8*)(hp + rt * 16 * HSTR + ks * 32);
        #pragma unroll
        for (int j = 0; j < 2; ++j)
            b[j] = w2f[(size_t)((w * 2 + j) * 16 + ks) * 64 + l];
        #pragma unroll
        for (int rt = 0; rt < 4; ++rt)
            #pragma unroll
            for (int j = 0; j < 2; ++j)
                acc2[rt][j] = __builtin_amdgcn_mfma_f32_16x16x32_bf16(a[rt], b[j], acc2[rt][j], 0, 0, 0);
    }

    // epilogue: +b2, l2norm (16-lane shfl + LDS atomic across 4 waves), store
    float v[4][2][4];
    #pragma unroll
    for (int rt = 0; rt < 4; ++rt)
        #pragma unroll
        for (int j = 0; j < 2; ++j) {
            float bias = b2s[w * 32 + j * 16 + c];
            #pragma unroll
            for (int reg = 0; reg < 4; ++reg)
                v[rt][j][reg] = acc2[rt][j][reg] + bias;
        }
    #pragma unroll
    for (int rt = 0; rt < 4; ++rt)
        #pragma unroll
        for (int reg = 0; reg < 4; ++reg) {
            float s = v[rt][0][reg] * v[rt][0][reg] + v[rt][1][reg] * v[rt][1][reg];
            s += __shfl_xor(s, 1); s += __shfl_xor(s, 2);
            s += __shfl_xor(s, 4); s += __shfl_xor(s, 8);
            if (c == 0) atomicAdd(&sumsq[rt * 16 + q * 4 + reg], s);
        }
    __syncthreads();
    #pragma unroll
    for (int rt = 0; rt < 4; ++rt)
        #pragma unroll
        for (int reg = 0; reg < 4; ++reg) {
            int row = rt * 16 + q * 4 + reg;
            if (row < nval) {
                float inv = 1.0f / fmaxf(sqrtf(sumsq[row]), 1e-12f);
                #pragma unroll
                for (int j = 0; j < 2; ++j) {
                    int col = w * 32 + j * 16 + c;
                    float o = v[rt][j][reg] * inv;
                    if (OUT_BF16)
                        ((unsigned short*)outp)[(size_t)(row0 + row) * 128 + col] = f2bf(o);
                    else
                        ((float*)outp)[(size_t)(row0 + row) * 128 + col] = o;
                }
            }
        }
}

#define ASI 392   // item A stride (384+8): 784 B = 49*16 -> even bank spread
#define ASU 264   // user A stride (256+8): 528 B = 33*16

__global__ __launch_bounds__(256, 2) void item_kernel(
    const float* __restrict__ text, const float* __restrict__ gcn,
    const bf8* __restrict__ w1f, const float* __restrict__ b1,
    const bf8* __restrict__ w2f, const float* __restrict__ b2,
    unsigned short* __restrict__ item_bf)
{
    __shared__ __align__(16) unsigned short U[64 * 520];   // 66.6 KB union A/H
    __shared__ float b1s[512], b2s[128], sumsq[64];
    const int tid = threadIdx.x;
    const int row0 = blockIdx.x * 64;
    const int nval = min(64, N_ITEMS - row0);
    const float4* t4 = (const float4*)text;
    const float4* g4 = (const float4*)gcn;
    #pragma unroll
    for (int j = 0; j < 16; ++j) {            // text: 64 x 256
        int idx = tid + j * 256; int r = idx >> 6, c4 = idx & 63;
        float4 x = (r < nval) ? t4[(size_t)(row0 + r) * 64 + c4] : make_float4(0.f,0.f,0.f,0.f);
        ushort4 s; s.x = f2bf(x.x); s.y = f2bf(x.y); s.z = f2bf(x.z); s.w = f2bf(x.w);
        *(ushort4*)(U + r * ASI + c4 * 4) = s;
    }
    #pragma unroll
    for (int j = 0; j < 8; ++j) {             // gcn: 64 x 128
        int idx = tid + j * 256; int r = idx >> 5, c4 = idx & 31;
        float4 x = (r < nval) ? g4[(size_t)(row0 + r) * 32 + c4] : make_float4(0.f,0.f,0.f,0.f);
        ushort4 s; s.x = f2bf(x.x); s.y = f2bf(x.y); s.z = f2bf(x.z); s.w = f2bf(x.w);
        *(ushort4*)(U + r * ASI + 256 + c4 * 4) = s;
    }
    b1s[tid] = b1[tid]; b1s[tid + 256] = b1[tid + 256];
    if (tid < 128) b2s[tid] = b2[tid];
    if (tid < 64)  sumsq[tid] = 0.0f;
    __syncthreads();
    tower_core<12, ASI, true>(U, b1s, b2s, sumsq, w1f, w2f, item_bf, row0, nval, tid);
}

__global__ __launch_bounds__(256, 2) void user_kernel(
    const float* __restrict__ gcnu, const int* __restrict__ hist,
    const unsigned short* __restrict__ item_bf,
    const bf8* __restrict__ w1f, const float* __restrict__ b1,
    const bf8* __restrict__ w2f, const float* __restrict__ b2,
    float* __restrict__ outp)
{
    __shared__ __align__(16) unsigned short U[64 * 520];   // union A/H
    __shared__ float b1s[512], b2s[128], sumsq[64];
    const int tid = threadIdx.x;
    const int u0 = blockIdx.x * 64;
    const float4* g4 = (const float4*)gcnu;
    #pragma unroll
    for (int j = 0; j < 8; ++j) {             // gcn_user: 64 x 128 -> cols 0..127
        int idx = tid + j * 256; int r = idx >> 5, c4 = idx & 31;
        float4 x = g4[(size_t)(u0 + r) * 32 + c4];
        ushort4 s; s.x = f2bf(x.x); s.y = f2bf(x.y); s.z = f2bf(x.z); s.w = f2bf(x.w);
        *(ushort4*)(U + r * ASU + c4 * 4) = s;
    }
    b1s[tid] = b1[tid]; b1s[tid + 256] = b1[tid + 256];
    if (tid < 128) b2s[tid] = b2[tid];
    if (tid < 64)  sumsq[tid] = 0.0f;
    // gather + mean -> cols 128..255. 4 threads/user, 64 B (32 elems) each.
    {
        const int u = tid >> 2, g = tid & 3;
        float f[32];
        #pragma unroll
        for (int k = 0; k < 32; ++k) f[k] = 0.0f;
        const int* hrow = hist + (size_t)(u0 + u) * HIST;
        #pragma unroll 5
        for (int t = 0; t < HIST; ++t) {
            int id = hrow[t];
            const uint4* p = (const uint4*)(item_bf + (size_t)id * 128 + g * 32);
            #pragma unroll
            for (int h = 0; h < 4; ++h) {
                uint4 x = p[h];
                unsigned vs[4] = {x.x, x.y, x.z, x.w};
                #pragma unroll
                for (int k = 0; k < 4; ++k) {
                    f[h * 8 + 2 * k]     += bf2f(vs[k] & 0xffffu);
                    f[h * 8 + 2 * k + 1] += bf2f(vs[k] >> 16);
                }
            }
        }
        unsigned o[16];
        #pragma unroll
        for (int k = 0; k < 16; ++k)
            o[k] = (unsigned)f2bf(f[2 * k] * 0.02f) | ((unsigned)f2bf(f[2 * k + 1] * 0.02f) << 16);
        unsigned short* dstp = U + u * ASU + 128 + g * 32;
        #pragma unroll
        for (int h = 0; h < 4; ++h) {
            uint4 s; s.x = o[h*4]; s.y = o[h*4+1]; s.z = o[h*4+2]; s.w = o[h*4+3];
            *(uint4*)(dstp + h * 8) = s;
        }
    }
    __syncthreads();
    tower_core<8, ASU, false>(U, b1s, b2s, sumsq, w1f, w2f, outp, u0, 64, tid);
}

extern "C" void kernel_launch(void* const* d_in, const int* in_sizes, int n_in,
                              void* d_out, int out_size, void* d_ws, size_t ws_size,
                              hipStream_t stream) {
    const float* text = (const float*)d_in[0];   // [100000,256]
    const float* gcni = (const float*)d_in[1];   // [100000,128]
    const float* gcnu = (const float*)d_in[2];   // [16384,128]
    const int*   hist = (const int*)d_in[3];     // [16384,50]
    const float* W1i  = (const float*)d_in[4];   // [384,512]
    const float* b1i  = (const float*)d_in[5];
    const float* W2i  = (const float*)d_in[6];   // [512,128]
    const float* b2i  = (const float*)d_in[7];
    const float* W1u  = (const float*)d_in[8];   // [256,512]
    const float* b1u  = (const float*)d_in[9];
    const float* W2u  = (const float*)d_in[10];  // [512,128]
    const float* b2u  = (const float*)d_in[11];
    float* out = (float*)d_out;                  // [16384,128] fp32

    unsigned short* itemb = (unsigned short*)d_ws;   // 25.6 MB bf16 item_emb
    unsigned short* pw = itemb + 12800000;           // packed weights (0.9 MB)

    pack_weights<<<224, 256, 0, stream>>>(W1i, W2i, W1u, W2u, pw);
    item_kernel<<<(N_ITEMS + 63) / 64, 256, 0, stream>>>(
        text, gcni, (const bf8*)pw, b1i, (const bf8*)(pw + 196608), b2i, itemb);
    user_kernel<<<N_USERS / 64, 256, 0, stream>>>(
        gcnu, hist, itemb, (const bf8*)(pw + 262144), b1u, (const bf8*)(pw + 393216), b2u, out);
}